// Round 25
// baseline (190.359 us; speedup 1.0000x reference)
//
#include <hip/hip_runtime.h>
#include <stdint.h>

typedef float f32x4 __attribute__((ext_vector_type(4)));
typedef int   i32x8 __attribute__((ext_vector_type(8)));

// ArcFace constants (margin=0.5, scale=70)
constexpr float COS_M = 0.8775825618903728f;
constexpr float SIN_M = 0.4794255386042030f;
constexpr float MM    = 0.2397127693021015f;   // sin(pi-0.5)*0.5
constexpr float SCALE = 70.0f;
constexpr float LOG2E = 1.4426950408889634f;
constexpr float CA =  SCALE * COS_M * LOG2E;   // coeff on cos
constexpr float CB =  SCALE * SIN_M * LOG2E;   // coeff on sin
constexpr float CC = -SCALE * LOG2E;           // -70 shift, log2 domain

// skip threshold: c < 0.30 -> tt < -120.6 (log2); measured absmax 0.0625
// (threshold 0.2) across R5-R24, deterministic. Per-m 4-value gate.
constexpr float C0 = 0.30f;
constexpr int SCL1 = 0x7f7f7f7f;               // E8M0 127 = 1.0 per 32-block

constexpr int NB = 2048, NC = 100000, ND = 128;
constexpr int NCP = 102400;                    // padded classes = 128 cg x 800
constexpr unsigned GRID_MAIN = 2048;
// k_main: R19/R22 structure (2048 blocks = 16 rb x 128 cg, 8 waves/SIMD,
// zero LDS/barriers, B fragment-major L2-resident, mfma_scale K=128,
// depth-3 B-prefetch, T15 acc double-pipeline) + LAST-BLOCK FINALIZE:
// counter-gated tail block runs the logsumexp finalize (saves k_final
// launch). rowsum atomics are device-scope (G12); threadfence release/
// acquire around the counter.

// scaled-K128 fragment-major dword index for dword d (0..31) of class-col c
__device__ __forceinline__ uint32_t widx(int c, int d) {
  return (uint32_t)((c >> 4) * 512 + (d >> 3) * 128 + (c & 15) * 8 + (d & 7));
}

// ---- fused normalize + target-cos; also zeroes rowsum and the counter ----
// blocks [0,12800): w rows (8/block) -> wn32 (frag-major fp8)
// blocks [12800,13056): x rows -> xn32 (linear fp8); rowsum+counter zero
// blocks [13056,13312): target-cos, quantization replicated bitwise
__global__ void __launch_bounds__(256) k_norm(const float* __restrict__ x,
                                              const float* __restrict__ w,
                                              const int* __restrict__ tgt,
                                              uint32_t* __restrict__ xn32,
                                              uint32_t* __restrict__ wn32,
                                              float* __restrict__ rowsum,
                                              float2* __restrict__ cost,
                                              unsigned* __restrict__ counter) {
  const int wv = threadIdx.x >> 6, lane = threadIdx.x & 63;
  const int h = lane >> 5, j = lane & 31;
  if (blockIdx.x < 12800) {
    const int c = blockIdx.x * 8 + wv * 2 + h;
    if (c >= NC) { wn32[widx(c, j)] = 0u; return; }
    const float4 f = reinterpret_cast<const float4*>(w + (size_t)c * ND)[j];
    float ss = f.x * f.x + f.y * f.y + f.z * f.z + f.w * f.w;
    #pragma unroll
    for (int off = 1; off < 32; off <<= 1) ss += __shfl_xor(ss, off, 64);
    const float sc = __builtin_amdgcn_rsqf(fmaxf(ss, 1e-24f));
    int pk = __builtin_amdgcn_cvt_pk_fp8_f32(f.x * sc, f.y * sc, 0, false);
    pk = __builtin_amdgcn_cvt_pk_fp8_f32(f.z * sc, f.w * sc, pk, true);
    wn32[widx(c, j)] = (uint32_t)pk;
  } else if (blockIdx.x < 13056) {
    const int bx = blockIdx.x - 12800;                  // 0..255
    if (bx < 8) rowsum[bx * 256 + threadIdx.x] = 0.0f;
    if (bx == 8 && threadIdx.x == 0) *counter = 0u;
    const int row = bx * 8 + wv * 2 + h;
    const float4 f = reinterpret_cast<const float4*>(x + (size_t)row * ND)[j];
    float ss = f.x * f.x + f.y * f.y + f.z * f.z + f.w * f.w;
    #pragma unroll
    for (int off = 1; off < 32; off <<= 1) ss += __shfl_xor(ss, off, 64);
    const float sc = __builtin_amdgcn_rsqf(fmaxf(ss, 1e-24f));
    int pk = __builtin_amdgcn_cvt_pk_fp8_f32(f.x * sc, f.y * sc, 0, false);
    pk = __builtin_amdgcn_cvt_pk_fp8_f32(f.z * sc, f.w * sc, pk, true);
    xn32[row * 32 + j] = (uint32_t)pk;
  } else {
    const int b = (blockIdx.x - 13056) * 8 + wv * 2 + h;  // 0..2047
    const int t = tgt[b];
    const float4 fx = reinterpret_cast<const float4*>(x + (size_t)b * ND)[j];
    const float4 fw = reinterpret_cast<const float4*>(w + (size_t)t * ND)[j];
    float ssx = fx.x * fx.x + fx.y * fx.y + fx.z * fx.z + fx.w * fx.w;
    float ssw = fw.x * fw.x + fw.y * fw.y + fw.z * fw.z + fw.w * fw.w;
    float dot = fx.x * fw.x + fx.y * fw.y + fx.z * fw.z + fx.w * fw.w;
    #pragma unroll
    for (int off = 1; off < 32; off <<= 1) {
      ssx += __shfl_xor(ssx, off, 64);
      ssw += __shfl_xor(ssw, off, 64);
      dot += __shfl_xor(dot, off, 64);
    }
    const float scx = __builtin_amdgcn_rsqf(fmaxf(ssx, 1e-24f));
    const float scw = __builtin_amdgcn_rsqf(fmaxf(ssw, 1e-24f));
    int pkx = __builtin_amdgcn_cvt_pk_fp8_f32(fx.x * scx, fx.y * scx, 0, false);
    pkx = __builtin_amdgcn_cvt_pk_fp8_f32(fx.z * scx, fx.w * scx, pkx, true);
    int pkw = __builtin_amdgcn_cvt_pk_fp8_f32(fw.x * scw, fw.y * scw, 0, false);
    pkw = __builtin_amdgcn_cvt_pk_fp8_f32(fw.z * scw, fw.w * scw, pkw, true);
    float dq = 0.0f;
    dq += __builtin_amdgcn_cvt_f32_fp8(pkx, 0) * __builtin_amdgcn_cvt_f32_fp8(pkw, 0);
    dq += __builtin_amdgcn_cvt_f32_fp8(pkx, 1) * __builtin_amdgcn_cvt_f32_fp8(pkw, 1);
    dq += __builtin_amdgcn_cvt_f32_fp8(pkx, 2) * __builtin_amdgcn_cvt_f32_fp8(pkw, 2);
    dq += __builtin_amdgcn_cvt_f32_fp8(pkx, 3) * __builtin_amdgcn_cvt_f32_fp8(pkw, 3);
    #pragma unroll
    for (int off = 1; off < 32; off <<= 1) dq += __shfl_xor(dq, off, 64);
    if (j == 0) {
      const float de = dot / (sqrtf(ssx) * sqrtf(ssw));
      cost[b] = make_float2(de, dq);
    }
  }
}

// ---- main fused GEMM + last-block finalize ----
__global__ void __launch_bounds__(256, 4) k_main(const uint32_t* __restrict__ xn32,
                                                 const uint32_t* __restrict__ wn32,
                                                 float* __restrict__ rowsum,
                                                 const float2* __restrict__ cost,
                                                 unsigned* __restrict__ counter,
                                                 float* __restrict__ out) {
  const int wv = threadIdx.x >> 6, lane = threadIdx.x & 63;
  const int q = lane >> 4, r = lane & 15;
  // XCD-affine: xcd = b&7 owns cgs [16*xcd, 16*xcd+16)  (1.6MB/XCD L2-resident)
  const int xcd = blockIdx.x & 7, idx = blockIdx.x >> 3;  // idx 0..255
  const int cg = xcd * 16 + (idx >> 4);                 // 0..127
  const int rb = idx & 15;                              // 0..15
  const int rowbase = rb * 128 + wv * 32;
  const int fragbase = cg * 50;                         // 50 16-col frags per cg

  // A fragments: m=2 x (16 rows); direct i32x8 deref -> 2x dwordx4, no movs
  i32x8 afrag[2];
  #pragma unroll
  for (int m = 0; m < 2; ++m)
    afrag[m] = *reinterpret_cast<const i32x8*>(
        xn32 + (size_t)(rowbase + 16 * m + r) * 32 + q * 8);

  float rsum[2][4] = {{0.f,0.f,0.f,0.f},{0.f,0.f,0.f,0.f}};

  auto loadB = [&](i32x8* buf, int nn) {
    *buf = *reinterpret_cast<const i32x8*>(
        wn32 + (size_t)(fragbase + nn) * 512 + q * 128 + r * 8);
  };
  auto mfmaStep = [&](const i32x8& buf, f32x4* acc) {
    __builtin_amdgcn_s_setprio(1);
    #pragma unroll
    for (int m = 0; m < 2; ++m)
      acc[m] = __builtin_amdgcn_mfma_scale_f32_16x16x128_f8f6f4(
          afrag[m], buf, (f32x4){0.f, 0.f, 0.f, 0.f},
          0 /*A=fp8*/, 0 /*B=fp8*/, 0, SCL1, 0, SCL1);
    __builtin_amdgcn_s_setprio(0);
  };
  auto epi = [&](const f32x4* acc) {
    #pragma unroll
    for (int m = 0; m < 2; ++m) {
      const float mx = fmaxf(fmaxf(acc[m][0], acc[m][1]),
                             fmaxf(acc[m][2], acc[m][3]));
      if (__any(mx > C0)) {
        #pragma unroll
        for (int e = 0; e < 4; ++e) {
          const float c = acc[m][e];
          const float s2 = fmaxf(fmaf(-c, c, 1.0f), 0.0f);
          const float sn = __builtin_amdgcn_sqrtf(s2);
          float tt = fmaf(c, CA, CC);
          tt = fmaf(sn, -CB, tt);
          rsum[m][e] += __builtin_amdgcn_exp2f(tt);
        }
      }
    }
  };

  // depth-3 B-prefetch (4 named buffers) + epilogue double-pipeline
  i32x8 b0, b1, b2, b3;
  f32x4 aA[2], aB[2];
  loadB(&b0, 0);
  loadB(&b1, 1);
  loadB(&b2, 2);
  mfmaStep(b0, aA);
  for (int nn = 0; nn < 48; nn += 4) {
    loadB(&b3, nn + 3);                   mfmaStep(b1, aB);  epi(aA);  // frag nn
    if (nn + 4 < 50) loadB(&b0, nn + 4);  mfmaStep(b2, aA);  epi(aB);  // frag nn+1
    if (nn + 5 < 50) loadB(&b1, nn + 5);  mfmaStep(b3, aB);  epi(aA);  // frag nn+2
    if (nn + 6 < 50) loadB(&b2, nn + 6);  mfmaStep(b0, aA);  epi(aB);  // frag nn+3
  }
  mfmaStep(b1, aB);
  epi(aA);                                // frag 48
  epi(aB);                                // frag 49

  // reduce over the 16 class-lanes, then one atomic per row
  #pragma unroll
  for (int m = 0; m < 2; ++m)
    #pragma unroll
    for (int e = 0; e < 4; ++e) {
      float v = rsum[m][e];
      #pragma unroll
      for (int off = 1; off < 16; off <<= 1) v += __shfl_xor(v, off, 64);
      if (r == 0)
        atomicAdd(&rowsum[rowbase + 16 * m + 4 * q + e], v);
    }

  // ---- last-block finalize (threadfence-counter pattern) ----
  __threadfence();                        // release this block's rowsum adds
  __syncthreads();
  __shared__ bool last;
  if (threadIdx.x == 0)
    last = (atomicAdd(counter, 1u) == GRID_MAIN - 1u);
  __syncthreads();
  if (!last) return;
  __threadfence();                        // acquire all blocks' rowsum adds

  __shared__ float red[256];
  float part = 0.f;
  for (int b = threadIdx.x; b < NB; b += 256) {
    const float2 cb = cost[b];
    const float ce = fminf(cb.x, 1.0f);                       // exact cos (clip)
    const float cq = cb.y;                                    // fp8-replica cos
    const float s2 = fmaxf(fmaf(-cq, cq, 1.0f), 0.0f);
    const float sn = __builtin_amdgcn_sqrtf(s2);
    float tt = fmaf(cq, CA, CC);
    tt = fmaf(sn, -CB, tt);
    // k_main's add for the target column: fires iff its m-group max > C0;
    // group-max >= cq, and when cq <= C0 the term is <=5e-37 (negligible).
    const float v_ctm = (cq > C0) ? __builtin_amdgcn_exp2f(tt) : 0.0f;
    const float logit_t = SCALE * (ce - MM);                  // true target logit
    const float v_tgt = __builtin_amdgcn_exp2f((logit_t - SCALE) * LOG2E);
    float sum = rowsum[b] - v_ctm + v_tgt;
    sum = fmaxf(sum, 1e-37f);
    part += __builtin_amdgcn_logf(sum) * 0.6931471805599453f + SCALE - logit_t;
  }
  red[threadIdx.x] = part;
  __syncthreads();
  #pragma unroll
  for (int s = 128; s > 0; s >>= 1) {
    if (threadIdx.x < s) red[threadIdx.x] += red[threadIdx.x + s];
    __syncthreads();
  }
  if (threadIdx.x == 0) out[0] = red[0] * (1.0f / NB);
}

extern "C" void kernel_launch(void* const* d_in, const int* in_sizes, int n_in,
                              void* d_out, int out_size, void* d_ws, size_t ws_size,
                              hipStream_t stream) {
  const float* x   = (const float*)d_in[0];
  const int*   tgt = (const int*)d_in[1];
  const float* w   = (const float*)d_in[2];
  float* out = (float*)d_out;

  char* ws = (char*)d_ws;
  const size_t WN_B = (size_t)NCP * 128;       // 13,107,200
  const size_t XN_B = (size_t)NB * 128;        // 262,144
  uint32_t* wn32   = (uint32_t*)ws;
  uint32_t* xn32   = (uint32_t*)(ws + WN_B);
  float2*   cost   = (float2*)(ws + WN_B + XN_B);
  float*    rowsum = (float*)(ws + WN_B + XN_B + (size_t)NB * 8);
  unsigned* counter = (unsigned*)(ws + WN_B + XN_B + (size_t)NB * 12);
  if (ws_size < WN_B + XN_B + (size_t)NB * 12 + 4) return;

  k_norm <<<13312, 256, 0, stream>>>(x, w, tgt, xn32, wn32, rowsum, cost, counter);
  k_main <<<GRID_MAIN, 256, 0, stream>>>(xn32, wn32, rowsum, cost, counter, out);
}

// Round 26
// 57.153 us; speedup vs baseline: 3.3307x; 3.3307x over previous
//
#include <hip/hip_runtime.h>
#include <stdint.h>

typedef float f32x4 __attribute__((ext_vector_type(4)));
typedef int   i32x8 __attribute__((ext_vector_type(8)));

// ArcFace constants (margin=0.5, scale=70)
constexpr float COS_M = 0.8775825618903728f;
constexpr float SIN_M = 0.4794255386042030f;
constexpr float MM    = 0.2397127693021015f;   // sin(pi-0.5)*0.5
constexpr float SCALE = 70.0f;
constexpr float LOG2E = 1.4426950408889634f;
constexpr float CA =  SCALE * COS_M * LOG2E;   // coeff on cos
constexpr float CB =  SCALE * SIN_M * LOG2E;   // coeff on sin
constexpr float CC = -SCALE * LOG2E;           // -70 shift, log2 domain

// skip threshold: c < 0.30 -> tt < -120.6 (log2); measured absmax 0.0625
// (threshold 0.2) across R5-R24, deterministic. Per-m 4-value gate.
constexpr float C0 = 0.30f;
constexpr int SCL1 = 0x7f7f7f7f;               // E8M0 127 = 1.0 per 32-block

constexpr int NB = 2048, NC = 100000, ND = 128;
constexpr int NCP = 102400;                    // padded classes = 128 cg x 800
// R24 configuration (57.8us, session best). R25's last-block finalize
// regressed 3.3x: __threadfence() emits device-scope L2 writeback/inv,
// destroying the L2-resident wn32 the kernel depends on. Reverted.

// scaled-K128 fragment-major dword index for dword d (0..31) of class-col c
__device__ __forceinline__ uint32_t widx(int c, int d) {
  return (uint32_t)((c >> 4) * 512 + (d >> 3) * 128 + (c & 15) * 8 + (d & 7));
}

// ---- fused normalize + target-cos ----
// blocks [0,12800): w rows (8/block) -> wn32 (frag-major fp8)
// blocks [12800,13056): x rows (8/block) -> xn32 (linear fp8); rowsum zero
// blocks [13056,13312): target-cos (8 rows/block), quantization REPLICATED
//   bitwise (same float4 read, same 5-step half-wave reduce, same cvt_pk).
__global__ void __launch_bounds__(256) k_norm(const float* __restrict__ x,
                                              const float* __restrict__ w,
                                              const int* __restrict__ tgt,
                                              uint32_t* __restrict__ xn32,
                                              uint32_t* __restrict__ wn32,
                                              float* __restrict__ rowsum,
                                              float2* __restrict__ cost) {
  const int wv = threadIdx.x >> 6, lane = threadIdx.x & 63;
  const int h = lane >> 5, j = lane & 31;
  if (blockIdx.x < 12800) {
    const int c = blockIdx.x * 8 + wv * 2 + h;
    if (c >= NC) { wn32[widx(c, j)] = 0u; return; }
    const float4 f = reinterpret_cast<const float4*>(w + (size_t)c * ND)[j];
    float ss = f.x * f.x + f.y * f.y + f.z * f.z + f.w * f.w;
    #pragma unroll
    for (int off = 1; off < 32; off <<= 1) ss += __shfl_xor(ss, off, 64);
    const float sc = __builtin_amdgcn_rsqf(fmaxf(ss, 1e-24f));
    int pk = __builtin_amdgcn_cvt_pk_fp8_f32(f.x * sc, f.y * sc, 0, false);
    pk = __builtin_amdgcn_cvt_pk_fp8_f32(f.z * sc, f.w * sc, pk, true);
    wn32[widx(c, j)] = (uint32_t)pk;
  } else if (blockIdx.x < 13056) {
    const int bx = blockIdx.x - 12800;                  // 0..255
    if (bx < 8) rowsum[bx * 256 + threadIdx.x] = 0.0f;
    const int row = bx * 8 + wv * 2 + h;
    const float4 f = reinterpret_cast<const float4*>(x + (size_t)row * ND)[j];
    float ss = f.x * f.x + f.y * f.y + f.z * f.z + f.w * f.w;
    #pragma unroll
    for (int off = 1; off < 32; off <<= 1) ss += __shfl_xor(ss, off, 64);
    const float sc = __builtin_amdgcn_rsqf(fmaxf(ss, 1e-24f));
    int pk = __builtin_amdgcn_cvt_pk_fp8_f32(f.x * sc, f.y * sc, 0, false);
    pk = __builtin_amdgcn_cvt_pk_fp8_f32(f.z * sc, f.w * sc, pk, true);
    xn32[row * 32 + j] = (uint32_t)pk;
  } else {
    const int b = (blockIdx.x - 13056) * 8 + wv * 2 + h;  // 0..2047
    const int t = tgt[b];
    const float4 fx = reinterpret_cast<const float4*>(x + (size_t)b * ND)[j];
    const float4 fw = reinterpret_cast<const float4*>(w + (size_t)t * ND)[j];
    float ssx = fx.x * fx.x + fx.y * fx.y + fx.z * fx.z + fx.w * fx.w;
    float ssw = fw.x * fw.x + fw.y * fw.y + fw.z * fw.z + fw.w * fw.w;
    float dot = fx.x * fw.x + fx.y * fw.y + fx.z * fw.z + fx.w * fw.w;
    #pragma unroll
    for (int off = 1; off < 32; off <<= 1) {
      ssx += __shfl_xor(ssx, off, 64);
      ssw += __shfl_xor(ssw, off, 64);
      dot += __shfl_xor(dot, off, 64);
    }
    // replicate quantization bitwise (same ops as the norm branches)
    const float scx = __builtin_amdgcn_rsqf(fmaxf(ssx, 1e-24f));
    const float scw = __builtin_amdgcn_rsqf(fmaxf(ssw, 1e-24f));
    int pkx = __builtin_amdgcn_cvt_pk_fp8_f32(fx.x * scx, fx.y * scx, 0, false);
    pkx = __builtin_amdgcn_cvt_pk_fp8_f32(fx.z * scx, fx.w * scx, pkx, true);
    int pkw = __builtin_amdgcn_cvt_pk_fp8_f32(fw.x * scw, fw.y * scw, 0, false);
    pkw = __builtin_amdgcn_cvt_pk_fp8_f32(fw.z * scw, fw.w * scw, pkw, true);
    float dq = 0.0f;
    dq += __builtin_amdgcn_cvt_f32_fp8(pkx, 0) * __builtin_amdgcn_cvt_f32_fp8(pkw, 0);
    dq += __builtin_amdgcn_cvt_f32_fp8(pkx, 1) * __builtin_amdgcn_cvt_f32_fp8(pkw, 1);
    dq += __builtin_amdgcn_cvt_f32_fp8(pkx, 2) * __builtin_amdgcn_cvt_f32_fp8(pkw, 2);
    dq += __builtin_amdgcn_cvt_f32_fp8(pkx, 3) * __builtin_amdgcn_cvt_f32_fp8(pkw, 3);
    #pragma unroll
    for (int off = 1; off < 32; off <<= 1) dq += __shfl_xor(dq, off, 64);
    if (j == 0) {
      const float de = dot / (sqrtf(ssx) * sqrtf(ssw));
      cost[b] = make_float2(de, dq);
    }
  }
}

// ---- main fused GEMM (MX-scaled fp8 K=128, global->VGPR B, no LDS/barriers) ----
__global__ void __launch_bounds__(256, 4) k_main(const uint32_t* __restrict__ xn32,
                                                 const uint32_t* __restrict__ wn32,
                                                 float* __restrict__ rowsum) {
  const int wv = threadIdx.x >> 6, lane = threadIdx.x & 63;
  const int q = lane >> 4, r = lane & 15;
  // XCD-affine: xcd = b&7 owns cgs [16*xcd, 16*xcd+16)  (1.6MB/XCD L2-resident)
  const int xcd = blockIdx.x & 7, idx = blockIdx.x >> 3;  // idx 0..255
  const int cg = xcd * 16 + (idx >> 4);                 // 0..127
  const int rb = idx & 15;                              // 0..15
  const int rowbase = rb * 128 + wv * 32;
  const int fragbase = cg * 50;                         // 50 16-col frags per cg

  // A fragments: m=2 x (16 rows); direct i32x8 deref -> 2x dwordx4, no movs
  i32x8 afrag[2];
  #pragma unroll
  for (int m = 0; m < 2; ++m)
    afrag[m] = *reinterpret_cast<const i32x8*>(
        xn32 + (size_t)(rowbase + 16 * m + r) * 32 + q * 8);

  float rsum[2][4] = {{0.f,0.f,0.f,0.f},{0.f,0.f,0.f,0.f}};

  auto loadB = [&](i32x8* buf, int nn) {
    *buf = *reinterpret_cast<const i32x8*>(
        wn32 + (size_t)(fragbase + nn) * 512 + q * 128 + r * 8);
  };
  auto mfmaStep = [&](const i32x8& buf, f32x4* acc) {
    __builtin_amdgcn_s_setprio(1);
    #pragma unroll
    for (int m = 0; m < 2; ++m)
      acc[m] = __builtin_amdgcn_mfma_scale_f32_16x16x128_f8f6f4(
          afrag[m], buf, (f32x4){0.f, 0.f, 0.f, 0.f},
          0 /*A=fp8*/, 0 /*B=fp8*/, 0, SCL1, 0, SCL1);
    __builtin_amdgcn_s_setprio(0);
  };
  auto epi = [&](const f32x4* acc) {
    #pragma unroll
    for (int m = 0; m < 2; ++m) {
      const float mx = fmaxf(fmaxf(acc[m][0], acc[m][1]),
                             fmaxf(acc[m][2], acc[m][3]));
      if (__any(mx > C0)) {
        #pragma unroll
        for (int e = 0; e < 4; ++e) {
          const float c = acc[m][e];
          const float s2 = fmaxf(fmaf(-c, c, 1.0f), 0.0f);
          const float sn = __builtin_amdgcn_sqrtf(s2);
          float tt = fmaf(c, CA, CC);
          tt = fmaf(sn, -CB, tt);
          rsum[m][e] += __builtin_amdgcn_exp2f(tt);
        }
      }
    }
  };

  // depth-3 B-prefetch (4 named buffers) + epilogue double-pipeline
  // (2 named acc sets). Invariant at loop top: aA = mfma(frag nn),
  // b1 = frag nn+1, b2 = frag nn+2, b3 about to load frag nn+3.
  i32x8 b0, b1, b2, b3;
  f32x4 aA[2], aB[2];
  loadB(&b0, 0);
  loadB(&b1, 1);
  loadB(&b2, 2);
  mfmaStep(b0, aA);
  for (int nn = 0; nn < 48; nn += 4) {
    loadB(&b3, nn + 3);                   mfmaStep(b1, aB);  epi(aA);  // frag nn
    if (nn + 4 < 50) loadB(&b0, nn + 4);  mfmaStep(b2, aA);  epi(aB);  // frag nn+1
    if (nn + 5 < 50) loadB(&b1, nn + 5);  mfmaStep(b3, aB);  epi(aA);  // frag nn+2
    if (nn + 6 < 50) loadB(&b2, nn + 6);  mfmaStep(b0, aA);  epi(aB);  // frag nn+3
  }
  // exit state: aA = mfma(frag 48), b1 = frag 49
  mfmaStep(b1, aB);
  epi(aA);                                // frag 48
  epi(aB);                                // frag 49

  // reduce over the 16 class-lanes, then one atomic per row
  #pragma unroll
  for (int m = 0; m < 2; ++m)
    #pragma unroll
    for (int e = 0; e < 4; ++e) {
      float v = rsum[m][e];
      #pragma unroll
      for (int off = 1; off < 16; off <<= 1) v += __shfl_xor(v, off, 64);
      if (r == 0)
        atomicAdd(&rowsum[rowbase + 16 * m + 4 * q + e], v);
    }
}

// ---- finalize: target-term swap, log, mean ----
__global__ void __launch_bounds__(256) k_final(const float* __restrict__ rowsum,
                                               const float2* __restrict__ cost,
                                               float* __restrict__ out) {
  __shared__ float red[256];
  float part = 0.f;
  for (int b = threadIdx.x; b < NB; b += 256) {
    const float2 cb = cost[b];
    const float ce = fminf(cb.x, 1.0f);                       // exact cos (clip)
    const float cq = cb.y;                                    // fp8-replica cos
    const float s2 = fmaxf(fmaf(-cq, cq, 1.0f), 0.0f);
    const float sn = __builtin_amdgcn_sqrtf(s2);
    float tt = fmaf(cq, CA, CC);
    tt = fmaf(sn, -CB, tt);
    // k_main's add for the target column: fires iff its m-group max > C0;
    // group-max >= cq, and when cq <= C0 the term is <=5e-37 (negligible
    // vs rowsum ~2^-105), so replicating with (cq > C0) matches.
    const float v_ctm = (cq > C0) ? __builtin_amdgcn_exp2f(tt) : 0.0f;
    const float logit_t = SCALE * (ce - MM);                  // true target logit
    const float v_tgt = __builtin_amdgcn_exp2f((logit_t - SCALE) * LOG2E);
    float sum = rowsum[b] - v_ctm + v_tgt;
    sum = fmaxf(sum, 1e-37f);
    part += __builtin_amdgcn_logf(sum) * 0.6931471805599453f + SCALE - logit_t;
  }
  red[threadIdx.x] = part;
  __syncthreads();
  #pragma unroll
  for (int s = 128; s > 0; s >>= 1) {
    if (threadIdx.x < s) red[threadIdx.x] += red[threadIdx.x + s];
    __syncthreads();
  }
  if (threadIdx.x == 0) out[0] = red[0] * (1.0f / NB);
}

extern "C" void kernel_launch(void* const* d_in, const int* in_sizes, int n_in,
                              void* d_out, int out_size, void* d_ws, size_t ws_size,
                              hipStream_t stream) {
  const float* x   = (const float*)d_in[0];
  const int*   tgt = (const int*)d_in[1];
  const float* w   = (const float*)d_in[2];
  float* out = (float*)d_out;

  char* ws = (char*)d_ws;
  const size_t WN_B = (size_t)NCP * 128;       // 13,107,200
  const size_t XN_B = (size_t)NB * 128;        // 262,144
  uint32_t* wn32   = (uint32_t*)ws;
  uint32_t* xn32   = (uint32_t*)(ws + WN_B);
  float2*   cost   = (float2*)(ws + WN_B + XN_B);
  float*    rowsum = (float*)(ws + WN_B + XN_B + NB * 8);
  if (ws_size < WN_B + XN_B + (size_t)NB * 12) return;

  k_norm <<<13312, 256, 0, stream>>>(x, w, tgt, xn32, wn32, rowsum, cost);
  k_main <<<2048,  256, 0, stream>>>(xn32, wn32, rowsum);
  k_final<<<1,     256, 0, stream>>>(rowsum, cost, out);
}

// Round 27
// 57.085 us; speedup vs baseline: 3.3346x; 1.0012x over previous
//
#include <hip/hip_runtime.h>
#include <stdint.h>

typedef float f32x4 __attribute__((ext_vector_type(4)));
typedef int   i32x8 __attribute__((ext_vector_type(8)));

// ArcFace constants (margin=0.5, scale=70)
constexpr float COS_M = 0.8775825618903728f;
constexpr float SIN_M = 0.4794255386042030f;
constexpr float MM    = 0.2397127693021015f;   // sin(pi-0.5)*0.5
constexpr float SCALE = 70.0f;
constexpr float LOG2E = 1.4426950408889634f;
constexpr float CA =  SCALE * COS_M * LOG2E;   // coeff on cos
constexpr float CB =  SCALE * SIN_M * LOG2E;   // coeff on sin
constexpr float CC = -SCALE * LOG2E;           // -70 shift, log2 domain

// skip threshold: c < 0.30 -> tt < -120.6 (log2); measured absmax 0.0625
// (threshold 0.2) across R5-R26, deterministic. Per-m 4-value gate.
constexpr float C0 = 0.30f;
constexpr int SCL1 = 0x7f7f7f7f;               // E8M0 127 = 1.0 per 32-block

constexpr int NB = 2048, NC = 100000, ND = 128;
constexpr int NCP = 102400;                    // padded classes = 128 cg x 800
// k_main: R24 structure with B-prefetch deepened 3 -> 5 frags ahead
// (6 named buffers, period-6 rotation): ~225-250 cyc lookahead vs the
// ~200-300 cyc L2 latency that the per-frag wall (~250 cyc) points to.

// scaled-K128 fragment-major dword index for dword d (0..31) of class-col c
__device__ __forceinline__ uint32_t widx(int c, int d) {
  return (uint32_t)((c >> 4) * 512 + (d >> 3) * 128 + (c & 15) * 8 + (d & 7));
}

// ---- fused normalize + target-cos ----
__global__ void __launch_bounds__(256) k_norm(const float* __restrict__ x,
                                              const float* __restrict__ w,
                                              const int* __restrict__ tgt,
                                              uint32_t* __restrict__ xn32,
                                              uint32_t* __restrict__ wn32,
                                              float* __restrict__ rowsum,
                                              float2* __restrict__ cost) {
  const int wv = threadIdx.x >> 6, lane = threadIdx.x & 63;
  const int h = lane >> 5, j = lane & 31;
  if (blockIdx.x < 12800) {
    const int c = blockIdx.x * 8 + wv * 2 + h;
    if (c >= NC) { wn32[widx(c, j)] = 0u; return; }
    const float4 f = reinterpret_cast<const float4*>(w + (size_t)c * ND)[j];
    float ss = f.x * f.x + f.y * f.y + f.z * f.z + f.w * f.w;
    #pragma unroll
    for (int off = 1; off < 32; off <<= 1) ss += __shfl_xor(ss, off, 64);
    const float sc = __builtin_amdgcn_rsqf(fmaxf(ss, 1e-24f));
    int pk = __builtin_amdgcn_cvt_pk_fp8_f32(f.x * sc, f.y * sc, 0, false);
    pk = __builtin_amdgcn_cvt_pk_fp8_f32(f.z * sc, f.w * sc, pk, true);
    wn32[widx(c, j)] = (uint32_t)pk;
  } else if (blockIdx.x < 13056) {
    const int bx = blockIdx.x - 12800;                  // 0..255
    if (bx < 8) rowsum[bx * 256 + threadIdx.x] = 0.0f;
    const int row = bx * 8 + wv * 2 + h;
    const float4 f = reinterpret_cast<const float4*>(x + (size_t)row * ND)[j];
    float ss = f.x * f.x + f.y * f.y + f.z * f.z + f.w * f.w;
    #pragma unroll
    for (int off = 1; off < 32; off <<= 1) ss += __shfl_xor(ss, off, 64);
    const float sc = __builtin_amdgcn_rsqf(fmaxf(ss, 1e-24f));
    int pk = __builtin_amdgcn_cvt_pk_fp8_f32(f.x * sc, f.y * sc, 0, false);
    pk = __builtin_amdgcn_cvt_pk_fp8_f32(f.z * sc, f.w * sc, pk, true);
    xn32[row * 32 + j] = (uint32_t)pk;
  } else {
    const int b = (blockIdx.x - 13056) * 8 + wv * 2 + h;  // 0..2047
    const int t = tgt[b];
    const float4 fx = reinterpret_cast<const float4*>(x + (size_t)b * ND)[j];
    const float4 fw = reinterpret_cast<const float4*>(w + (size_t)t * ND)[j];
    float ssx = fx.x * fx.x + fx.y * fx.y + fx.z * fx.z + fx.w * fx.w;
    float ssw = fw.x * fw.x + fw.y * fw.y + fw.z * fw.z + fw.w * fw.w;
    float dot = fx.x * fw.x + fx.y * fw.y + fx.z * fw.z + fx.w * fw.w;
    #pragma unroll
    for (int off = 1; off < 32; off <<= 1) {
      ssx += __shfl_xor(ssx, off, 64);
      ssw += __shfl_xor(ssw, off, 64);
      dot += __shfl_xor(dot, off, 64);
    }
    const float scx = __builtin_amdgcn_rsqf(fmaxf(ssx, 1e-24f));
    const float scw = __builtin_amdgcn_rsqf(fmaxf(ssw, 1e-24f));
    int pkx = __builtin_amdgcn_cvt_pk_fp8_f32(fx.x * scx, fx.y * scx, 0, false);
    pkx = __builtin_amdgcn_cvt_pk_fp8_f32(fx.z * scx, fx.w * scx, pkx, true);
    int pkw = __builtin_amdgcn_cvt_pk_fp8_f32(fw.x * scw, fw.y * scw, 0, false);
    pkw = __builtin_amdgcn_cvt_pk_fp8_f32(fw.z * scw, fw.w * scw, pkw, true);
    float dq = 0.0f;
    dq += __builtin_amdgcn_cvt_f32_fp8(pkx, 0) * __builtin_amdgcn_cvt_f32_fp8(pkw, 0);
    dq += __builtin_amdgcn_cvt_f32_fp8(pkx, 1) * __builtin_amdgcn_cvt_f32_fp8(pkw, 1);
    dq += __builtin_amdgcn_cvt_f32_fp8(pkx, 2) * __builtin_amdgcn_cvt_f32_fp8(pkw, 2);
    dq += __builtin_amdgcn_cvt_f32_fp8(pkx, 3) * __builtin_amdgcn_cvt_f32_fp8(pkw, 3);
    #pragma unroll
    for (int off = 1; off < 32; off <<= 1) dq += __shfl_xor(dq, off, 64);
    if (j == 0) {
      const float de = dot / (sqrtf(ssx) * sqrtf(ssw));
      cost[b] = make_float2(de, dq);
    }
  }
}

// ---- main fused GEMM (MX-scaled fp8 K=128, global->VGPR B, no LDS/barriers) ----
__global__ void __launch_bounds__(256, 4) k_main(const uint32_t* __restrict__ xn32,
                                                 const uint32_t* __restrict__ wn32,
                                                 float* __restrict__ rowsum) {
  const int wv = threadIdx.x >> 6, lane = threadIdx.x & 63;
  const int q = lane >> 4, r = lane & 15;
  // XCD-affine: xcd = b&7 owns cgs [16*xcd, 16*xcd+16)  (1.6MB/XCD L2-resident)
  const int xcd = blockIdx.x & 7, idx = blockIdx.x >> 3;  // idx 0..255
  const int cg = xcd * 16 + (idx >> 4);                 // 0..127
  const int rb = idx & 15;                              // 0..15
  const int rowbase = rb * 128 + wv * 32;
  const int fragbase = cg * 50;                         // 50 16-col frags per cg

  // A fragments: m=2 x (16 rows); direct i32x8 deref -> 2x dwordx4, no movs
  i32x8 afrag[2];
  #pragma unroll
  for (int m = 0; m < 2; ++m)
    afrag[m] = *reinterpret_cast<const i32x8*>(
        xn32 + (size_t)(rowbase + 16 * m + r) * 32 + q * 8);

  float rsum[2][4] = {{0.f,0.f,0.f,0.f},{0.f,0.f,0.f,0.f}};

  auto loadB = [&](i32x8* buf, int nn) {
    *buf = *reinterpret_cast<const i32x8*>(
        wn32 + (size_t)(fragbase + nn) * 512 + q * 128 + r * 8);
  };
  auto mfmaStep = [&](const i32x8& buf, f32x4* acc) {
    __builtin_amdgcn_s_setprio(1);
    #pragma unroll
    for (int m = 0; m < 2; ++m)
      acc[m] = __builtin_amdgcn_mfma_scale_f32_16x16x128_f8f6f4(
          afrag[m], buf, (f32x4){0.f, 0.f, 0.f, 0.f},
          0 /*A=fp8*/, 0 /*B=fp8*/, 0, SCL1, 0, SCL1);
    __builtin_amdgcn_s_setprio(0);
  };
  auto epi = [&](const f32x4* acc) {
    #pragma unroll
    for (int m = 0; m < 2; ++m) {
      const float mx = fmaxf(fmaxf(acc[m][0], acc[m][1]),
                             fmaxf(acc[m][2], acc[m][3]));
      if (__any(mx > C0)) {
        #pragma unroll
        for (int e = 0; e < 4; ++e) {
          const float c = acc[m][e];
          const float s2 = fmaxf(fmaf(-c, c, 1.0f), 0.0f);
          const float sn = __builtin_amdgcn_sqrtf(s2);
          float tt = fmaf(c, CA, CC);
          tt = fmaf(sn, -CB, tt);
          rsum[m][e] += __builtin_amdgcn_exp2f(tt);
        }
      }
    }
  };

  // depth-5 B-prefetch (6 named buffers, period-6 rotation) + acc dbuf.
  // Slot of frag F = F % 6. Loop-top invariant (nn = 0 mod 6):
  //   aA = mfma(frag nn); slots 1..4 hold frags nn+1..nn+4.
  i32x8 b0, b1, b2, b3, b4, b5;
  f32x4 aA[2], aB[2];
  loadB(&b0, 0);
  loadB(&b1, 1);
  loadB(&b2, 2);
  loadB(&b3, 3);
  loadB(&b4, 4);
  mfmaStep(b0, aA);
  for (int nn = 0; nn < 48; nn += 6) {
    loadB(&b5, nn + 5);                     mfmaStep(b1, aB);  epi(aA);  // frag nn
    loadB(&b0, nn + 6);                     mfmaStep(b2, aA);  epi(aB);  // frag nn+1
    loadB(&b1, nn + 7);                     mfmaStep(b3, aB);  epi(aA);  // frag nn+2
    if (nn + 8  < 50) loadB(&b2, nn + 8);   mfmaStep(b4, aA);  epi(aB);  // frag nn+3
    if (nn + 9  < 50) loadB(&b3, nn + 9);   mfmaStep(b5, aB);  epi(aA);  // frag nn+4
    if (nn + 10 < 50) loadB(&b4, nn + 10);  mfmaStep(b0, aA);  epi(aB);  // frag nn+5
  }
  // exit state: aA = mfma(frag 48); frag 49 is in slot 49%6 = 1
  mfmaStep(b1, aB);
  epi(aA);                                // frag 48
  epi(aB);                                // frag 49

  // reduce over the 16 class-lanes, then one atomic per row
  #pragma unroll
  for (int m = 0; m < 2; ++m)
    #pragma unroll
    for (int e = 0; e < 4; ++e) {
      float v = rsum[m][e];
      #pragma unroll
      for (int off = 1; off < 16; off <<= 1) v += __shfl_xor(v, off, 64);
      if (r == 0)
        atomicAdd(&rowsum[rowbase + 16 * m + 4 * q + e], v);
    }
}

// ---- finalize: target-term swap, log, mean ----
__global__ void __launch_bounds__(256) k_final(const float* __restrict__ rowsum,
                                               const float2* __restrict__ cost,
                                               float* __restrict__ out) {
  __shared__ float red[256];
  float part = 0.f;
  for (int b = threadIdx.x; b < NB; b += 256) {
    const float2 cb = cost[b];
    const float ce = fminf(cb.x, 1.0f);                       // exact cos (clip)
    const float cq = cb.y;                                    // fp8-replica cos
    const float s2 = fmaxf(fmaf(-cq, cq, 1.0f), 0.0f);
    const float sn = __builtin_amdgcn_sqrtf(s2);
    float tt = fmaf(cq, CA, CC);
    tt = fmaf(sn, -CB, tt);
    // k_main's add for the target column: fires iff its m-group max > C0;
    // group-max >= cq, and when cq <= C0 the term is <=5e-37 (negligible
    // vs rowsum ~2^-105), so replicating with (cq > C0) matches.
    const float v_ctm = (cq > C0) ? __builtin_amdgcn_exp2f(tt) : 0.0f;
    const float logit_t = SCALE * (ce - MM);                  // true target logit
    const float v_tgt = __builtin_amdgcn_exp2f((logit_t - SCALE) * LOG2E);
    float sum = rowsum[b] - v_ctm + v_tgt;
    sum = fmaxf(sum, 1e-37f);
    part += __builtin_amdgcn_logf(sum) * 0.6931471805599453f + SCALE - logit_t;
  }
  red[threadIdx.x] = part;
  __syncthreads();
  #pragma unroll
  for (int s = 128; s > 0; s >>= 1) {
    if (threadIdx.x < s) red[threadIdx.x] += red[threadIdx.x + s];
    __syncthreads();
  }
  if (threadIdx.x == 0) out[0] = red[0] * (1.0f / NB);
}

extern "C" void kernel_launch(void* const* d_in, const int* in_sizes, int n_in,
                              void* d_out, int out_size, void* d_ws, size_t ws_size,
                              hipStream_t stream) {
  const float* x   = (const float*)d_in[0];
  const int*   tgt = (const int*)d_in[1];
  const float* w   = (const float*)d_in[2];
  float* out = (float*)d_out;

  char* ws = (char*)d_ws;
  const size_t WN_B = (size_t)NCP * 128;       // 13,107,200
  const size_t XN_B = (size_t)NB * 128;        // 262,144
  uint32_t* wn32   = (uint32_t*)ws;
  uint32_t* xn32   = (uint32_t*)(ws + WN_B);
  float2*   cost   = (float2*)(ws + WN_B + XN_B);
  float*    rowsum = (float*)(ws + WN_B + XN_B + NB * 8);
  if (ws_size < WN_B + XN_B + (size_t)NB * 12) return;

  k_norm <<<13312, 256, 0, stream>>>(x, w, tgt, xn32, wn32, rowsum, cost);
  k_main <<<2048,  256, 0, stream>>>(xn32, wn32, rowsum);
  k_final<<<1,     256, 0, stream>>>(rowsum, cost, out);
}